// Round 6
// baseline (165.160 us; speedup 1.0000x reference)
//
#include <hip/hip_runtime.h>

#define NODE_IN 64
#define EDGE_IN 32
#define GLOBAL_IN 32
#define HID 128
#define EOUT 32

typedef float f32x4 __attribute__((ext_vector_type(4)));
typedef float f32x2 __attribute__((ext_vector_type(2)));
typedef short s16x8 __attribute__((ext_vector_type(8)));
typedef unsigned short u16x8 __attribute__((ext_vector_type(8)));

// native bf16 cast (RNE); pairs fuse into v_cvt_pk_bf16_f32
__device__ __forceinline__ unsigned short f2bf(float f) {
  __bf16 h = (__bf16)f;
  return __builtin_bit_cast(unsigned short, h);
}

__device__ __forceinline__ s16x8 cvt8(f32x4 a, f32x4 b) {
  u16x8 v = { f2bf(a[0]), f2bf(a[1]), f2bf(a[2]), f2bf(a[3]),
              f2bf(b[0]), f2bf(b[1]), f2bf(b[2]), f2bf(b[3]) };
  return __builtin_bit_cast(s16x8, v);
}

// ============================================================================
// Wave-independent design: each wave owns 16 edges end-to-end; ZERO per-tile
// barriers (rounds 1/3/5 were pinned at ~160us by 4-wave lockstep regardless
// of barrier count). W1 lives in LDS as 48 pre-swizzled B-fragments (frag f:
// lane l reads [f*1024 + l*16] -> conflict-free ds_read_b128). A-frags load
// direct from global (per-wave-exclusive rows, 1-tile-deep register prefetch;
// ebp 2 tiles deep to cover the ebp->u gather). H does a per-wave 4KB LDS
// round-trip (transpose D-layout -> A-layout), XOR-swizzled, no barrier.
//
// Column permutation (absorbed into weight staging, zero runtime cost):
// H orig col 16*(2p+e)+q  <->  stored col 32p+2q+e   (p=0..3, e=0..1, q=0..15)
// so the L1 epilogue writes packed b32 pairs; W2's K-rows and b1 use orig().
// Output cols permuted as before: lane r16 holds out cols 2r16, 2r16+1.
// ============================================================================
__global__ __launch_bounds__(256) void edge_mlp(
    const float* __restrict__ srcp, const float* __restrict__ dstp,
    const float* __restrict__ eap, const float* __restrict__ up,
    const int* __restrict__ ebp, const float* __restrict__ W1,
    const float* __restrict__ b1, const float* __restrict__ W2,
    const float* __restrict__ b2, float* __restrict__ outp,
    int E, int nt16)
{
  __shared__ __align__(16) unsigned short W1F[48 * 512];   // 48 KiB
  __shared__ __align__(16) unsigned short Hs[4][16 * 128]; // 16 KiB (4 KiB/wave)

  const int t = threadIdx.x;
  const int wid = t >> 6;
  const int lane = t & 63;
  const int g = lane >> 4;
  const int r16 = lane & 15;
  const int Em1 = E - 1;

  // ---- stage W1 fragments into LDS (once per block) ----
  // frag f = kk*8 + p*2 + e ; lane slot l holds W1[32kk+8*(l>>4)+j][16*(2p+e)+(l&15)]
  for (int s = t; s < 48 * 64; s += 256) {
    const int f = s >> 6, l = s & 63;
    const int kk = f >> 3, p = (f >> 1) & 3, e = f & 1;
    const int lg = l >> 4, lr = l & 15;
    const int col = 16 * (2 * p + e) + lr;
    u16x8 v;
#pragma unroll
    for (int j = 0; j < 8; ++j)
      v[j] = f2bf(W1[(32 * kk + 8 * lg + j) * HID + col]);
    *(u16x8*)&W1F[f * 512 + l * 8] = v;
  }

  // ---- W2 B-fragments in registers; K-index follows the stored-col order ----
  s16x8 w2f[4][2];
#pragma unroll
  for (int kk2 = 0; kk2 < 4; ++kk2) {
#pragma unroll
    for (int nt = 0; nt < 2; ++nt) {
      s16x8 v;
#pragma unroll
      for (int j = 0; j < 8; ++j) {
        const int s = 32 * kk2 + 8 * g + j;          // stored H col
        const int p = s >> 5, w = s & 31, q = w >> 1, e = w & 1;
        const int orig = 16 * (2 * p + e) + q;       // original H col
        v[j] = (short)f2bf(W2[orig * EOUT + 2 * r16 + nt]);
      }
      w2f[kk2][nt] = v;
    }
  }
  float b1pe[4][2];
#pragma unroll
  for (int p = 0; p < 4; ++p)
#pragma unroll
    for (int e = 0; e < 2; ++e)
      b1pe[p][e] = b1[16 * (2 * p + e) + r16];
  const float b2v0 = b2[2 * r16];
  const float b2v1 = b2[2 * r16 + 1];

  __syncthreads();   // the ONLY barrier: W1F ready; waves independent after this

  char* const hb = (char*)&Hs[wid][0];
  const int gw = blockIdx.x * 4 + wid;   // global wave id
  const int GW = gridDim.x * 4;

  if (gw >= nt16) return;

  // ---- prefetch state: 12 f32x4 = one 16-row tile of A-data ----
  f32x4 P[12];
  auto issueP = [&](int base, int eb) {
    const int row = min(base + r16, Em1);
    const float* ps = srcp + (size_t)row * NODE_IN + 8 * g;
    const float* pd = dstp + (size_t)row * NODE_IN + 8 * g;
    const float* pe = eap  + (size_t)row * EDGE_IN + 8 * g;
    const float* pu = up   + (size_t)eb  * GLOBAL_IN + 8 * g;
    P[0]  = *(const f32x4*)ps;        P[1]  = *(const f32x4*)(ps + 4);
    P[2]  = *(const f32x4*)(ps + 32); P[3]  = *(const f32x4*)(ps + 36);
    P[4]  = *(const f32x4*)pd;        P[5]  = *(const f32x4*)(pd + 4);
    P[6]  = *(const f32x4*)(pd + 32); P[7]  = *(const f32x4*)(pd + 36);
    P[8]  = *(const f32x4*)pe;        P[9]  = *(const f32x4*)(pe + 4);
    P[10] = *(const f32x4*)pu;        P[11] = *(const f32x4*)(pu + 4);
  };

  int wt = gw;
  {
    const int eb0 = ebp[min(wt * 16 + r16, Em1)];
    issueP(wt * 16, eb0);
  }
  int ebn = ebp[min((wt + GW) * 16 + r16, Em1)];

  for (; wt < nt16; wt += GW) {
    // ---- consume arrived P -> 6 A-frags; immediately re-issue next tile ----
    const s16x8 a0 = cvt8(P[0], P[1]);
    const s16x8 a1 = cvt8(P[2], P[3]);
    const s16x8 a2 = cvt8(P[4], P[5]);
    const s16x8 a3 = cvt8(P[6], P[7]);
    const s16x8 a4 = cvt8(P[8], P[9]);
    const s16x8 a5 = cvt8(P[10], P[11]);
    issueP((wt + GW) * 16, ebn);                    // loads fly over this tile
    ebn = ebp[min((wt + 2 * GW) * 16 + r16, Em1)];

    // ---- layer 1: 48 {ds_read_b128 B-frag, MFMA}, acc[p*2+e] ----
    f32x4 acc[8];
    {
      const f32x4 z = {0.f, 0.f, 0.f, 0.f};
#pragma unroll
      for (int i = 0; i < 8; ++i) acc[i] = z;
    }
#pragma unroll
    for (int kk = 0; kk < 6; ++kk) {
      const s16x8 a = (kk == 0) ? a0 : (kk == 1) ? a1 : (kk == 2) ? a2
                    : (kk == 3) ? a3 : (kk == 4) ? a4 : a5;
#pragma unroll
      for (int f2 = 0; f2 < 8; ++f2) {
        const s16x8 bf = *(const s16x8*)&W1F[(kk * 8 + f2) * 512 + lane * 8];
        acc[f2] = __builtin_amdgcn_mfma_f32_16x16x32_bf16(a, bf, acc[f2], 0, 0, 0);
      }
    }

    // ---- epilogue: +b1, relu, packed b32 into XOR-swizzled Hs ----
    // D-layout: row=4g+j, col(lane)=r16 -> stored col 32p+2r16+e
#pragma unroll
    for (int p = 0; p < 4; ++p) {
#pragma unroll
      for (int j = 0; j < 4; ++j) {
        const float h0 = fmaxf(acc[p * 2 + 0][j] + b1pe[p][0], 0.f);
        const float h1 = fmaxf(acc[p * 2 + 1][j] + b1pe[p][1], 0.f);
        const unsigned int pk = (unsigned int)f2bf(h0) |
                                ((unsigned int)f2bf(h1) << 16);
        const int row = 4 * g + j;
        int off = row * 256 + p * 64 + r16 * 4;
        off ^= (row & 7) << 4;
        *(unsigned int*)(hb + off) = pk;
      }
    }
    asm volatile("s_waitcnt lgkmcnt(0)" ::: "memory");
    __builtin_amdgcn_sched_barrier(0);              // rule #18: pin the wait

    // ---- layer 2: 4 swizzled b128 A-reads + 8 MFMA ----
    f32x4 acc2[2];
    {
      const f32x4 z = {0.f, 0.f, 0.f, 0.f};
      acc2[0] = z; acc2[1] = z;
    }
#pragma unroll
    for (int kk2 = 0; kk2 < 4; ++kk2) {
      int off = r16 * 256 + kk2 * 64 + g * 16;
      off ^= (r16 & 7) << 4;
      const s16x8 ah = *(const s16x8*)(hb + off);
      acc2[0] = __builtin_amdgcn_mfma_f32_16x16x32_bf16(ah, w2f[kk2][0], acc2[0], 0, 0, 0);
      acc2[1] = __builtin_amdgcn_mfma_f32_16x16x32_bf16(ah, w2f[kk2][1], acc2[1], 0, 0, 0);
    }
#pragma unroll
    for (int j = 0; j < 4; ++j) {
      const int m = wt * 16 + 4 * g + j;
      if (m < E) {
        f32x2 o = { acc2[0][j] + b2v0, acc2[1][j] + b2v1 };
        *(f32x2*)(outp + (size_t)m * EOUT + 2 * r16) = o;
      }
    }
  }
}

extern "C" void kernel_launch(void* const* d_in, const int* in_sizes, int n_in,
                              void* d_out, int out_size, void* d_ws, size_t ws_size,
                              hipStream_t stream) {
  const float* srcp = (const float*)d_in[0];
  const float* dstp = (const float*)d_in[1];
  const float* eap  = (const float*)d_in[2];
  const float* up   = (const float*)d_in[3];
  const int*   ebp  = (const int*)d_in[4];
  const float* W1   = (const float*)d_in[5];
  const float* b1   = (const float*)d_in[6];
  const float* W2   = (const float*)d_in[7];
  const float* b2   = (const float*)d_in[8];
  float* outp = (float*)d_out;

  const int E = in_sizes[0] / NODE_IN;
  const int nt16 = (E + 15) / 16;
  const int grid = 1024;   // 4096 waves, ~15 tiles/wave; 2 blocks/CU (64KB LDS)

  edge_mlp<<<grid, 256, 0, stream>>>(srcp, dstp, eap, up, ebp, W1, b1, W2, b2,
                                     outp, E, nt16);
}